// Round 6
// baseline (125.586 us; speedup 1.0000x reference)
//
#include <hip/hip_runtime.h>
#include <math.h>

#define NB 16
#define DIN 512
#define TT 4096
#define DCB 8
#define KC 1024
#define DQ 4                      // d-split chunks in K1
#define ZEP_OFF 10240             // ws float offset of ze_part
#define ZEP_FLOATS (NB * DQ * DCB * TT)
#define WS_NEED ((size_t)(ZEP_OFF + ZEP_FLOATS) * sizeof(float))

// ws layout (floats):
// [0,4096)      w_inT[d][c]
// [4096,8192)   w_out[o][c]
// [8192,9216)   cb2[k]
// [9216,10240)  commit partials (1024 main path / 512 fallback)
// [10240, +2097152)  ze_part[b][dq][c][t]   (main path only, 8 MB)

__global__ __launch_bounds__(512) void vq_setup(
    const float* __restrict__ in_v, const float* __restrict__ in_g,
    const float* __restrict__ out_v, const float* __restrict__ out_g,
    const float* __restrict__ cb, float* __restrict__ ws)
{
    int tid = threadIdx.x;
    float* w_inT = ws;
    float* w_out = ws + 4096;
    float* cb2   = ws + 8192;

    {   // w_in: 8 rows of 512; one wave per row
        int c    = tid >> 6;
        int lane = tid & 63;
        const float* v = in_v + c * DIN;
        float s = 0.f;
        #pragma unroll
        for (int i = 0; i < DIN; i += 64) {
            float x = v[i + lane];
            s += x * x;
        }
        #pragma unroll
        for (int off = 32; off > 0; off >>= 1) s += __shfl_xor(s, off, 64);
        float sq = sqrtf(s);
        float g  = in_g[c];
        #pragma unroll
        for (int i = 0; i < DIN; i += 64) {
            int d = i + lane;
            w_inT[d * DCB + c] = (g * v[d]) / sq;
        }
    }
    {   // w_out: 512 rows of 8
        int o = tid;
        const float* v = out_v + o * DCB;
        float s = 0.f;
        #pragma unroll
        for (int c = 0; c < DCB; ++c) s += v[c] * v[c];
        float sq = sqrtf(s);
        float g  = out_g[o];
        #pragma unroll
        for (int c = 0; c < DCB; ++c) w_out[o * DCB + c] = (g * v[c]) / sq;
    }
    for (int k = tid; k < KC; k += 512) {
        const float* r = cb + k * DCB;
        float s = 0.f;
        #pragma unroll
        for (int c = 0; c < DCB; ++c) s += r[c] * r[c];
        cb2[k] = s;
    }
}

// ---------------- main path ----------------

// K1: ze partials. grid = 16b x 4dq x 8tc, 256 thr. No LDS, no barriers.
__global__ __launch_bounds__(256) void vq_zepart(
    const float* __restrict__ z, const float* __restrict__ ws,
    float* __restrict__ zep)
{
    const float* w_inT = ws;
    int blk = blockIdx.x;
    int b   = blk >> 5;
    int dq  = (blk >> 3) & 3;
    int tc  = blk & 7;
    int t   = tc * 512 + 2 * threadIdx.x;

    const float* zp = z + (size_t)b * DIN * TT + t;

    float ze0[DCB], ze1[DCB];
    #pragma unroll
    for (int c = 0; c < DCB; ++c) { ze0[c] = 0.f; ze1[c] = 0.f; }

    int d0 = dq * 128;
    #pragma unroll 8
    for (int dd = 0; dd < 128; ++dd) {
        int d = d0 + dd;
        float2 zv = *(const float2*)(zp + (size_t)d * TT);   // 512 B/wave
        const float* wi = w_inT + d * DCB;                   // uniform -> s_load
        #pragma unroll
        for (int c = 0; c < DCB; ++c) {
            ze0[c] = fmaf(wi[c], zv.x, ze0[c]);
            ze1[c] = fmaf(wi[c], zv.y, ze1[c]);
        }
    }
    float* o = zep + ((size_t)(b * DQ + dq) * DCB) * TT + t;
    #pragma unroll
    for (int c = 0; c < DCB; ++c)
        *(float2*)(o + (size_t)c * TT) = make_float2(ze0[c], ze1[c]);
}

// K2: assemble ze, argmin scan (4-wave k-split), indices + commit partials.
// grid = 16b x 64tc, 256 thr. One barrier.
__global__ __launch_bounds__(256) void vq_scan(
    const float* __restrict__ cb, const float* __restrict__ in_b,
    const float* __restrict__ ws, float* __restrict__ ws_commit,
    float* __restrict__ out)
{
    const float* cb2 = ws + 8192;
    const float* zep = ws + ZEP_OFF;

    __shared__ float sd[4][64];
    __shared__ int   si[4][64];

    int w    = threadIdx.x >> 6;
    int wu   = __builtin_amdgcn_readfirstlane(w);
    int lane = threadIdx.x & 63;
    int blk  = blockIdx.x;
    int b    = blk >> 6;
    int t    = (blk & 63) * 64 + lane;

    // assemble ze from 4 partials + bias
    float ze[DCB];
    #pragma unroll
    for (int c = 0; c < DCB; ++c) ze[c] = 0.f;
    #pragma unroll
    for (int dq = 0; dq < DQ; ++dq) {
        const float* p = zep + ((size_t)(b * DQ + dq) * DCB) * TT + t;
        #pragma unroll
        for (int c = 0; c < DCB; ++c) ze[c] += p[(size_t)c * TT];  // 256 B/wave, L2
    }
    #pragma unroll
    for (int c = 0; c < DCB; ++c) ze[c] += in_b[c];

    float enc2 = 0.f;
    #pragma unroll
    for (int c = 0; c < DCB; ++c) enc2 += ze[c] * ze[c];

    // k-split scan: wave owns [wu*256, wu*256+256)
    float best = 3.4e38f;
    int   bi   = 0;
    int   k0   = wu * 256;
    #pragma unroll 4
    for (int kk = 0; kk < 256; ++kk) {
        int k = k0 + kk;
        const float* r = cb + k * DCB;       // uniform -> s_load_dwordx8
        float dot = 0.f;
        #pragma unroll
        for (int c = 0; c < DCB; ++c) dot = fmaf(ze[c], r[c], dot);
        float dk = (enc2 - 2.0f * dot) + cb2[k];
        if (dk < best) { best = dk; bi = k; }
    }
    sd[w][lane] = best;
    si[w][lane] = bi;
    __syncthreads();

    // ordered combine (strict < keeps first min over k)
    float gbest = sd[0][lane];
    int   gbi   = si[0][lane];
    #pragma unroll
    for (int w2 = 1; w2 < 4; ++w2) {
        float d2 = sd[w2][lane];
        int   i2 = si[w2][lane];
        if (d2 < gbest) { gbest = d2; gbi = i2; }
    }

    if (wu == 0) {
        const float* cq = cb + (size_t)gbi * DCB;   // divergent, L1
        float cl = 0.f;
        #pragma unroll
        for (int c = 0; c < DCB; ++c) {
            float diff = ze[c] - cq[c];
            cl = fmaf(diff, diff, cl);
        }
        #pragma unroll
        for (int off = 32; off > 0; off >>= 1) cl += __shfl_xor(cl, off, 64);
        if (lane == 0) ws_commit[blk] = cl;
        out[(size_t)NB * DIN * TT + NB + (size_t)b * TT + t] = (float)gbi;
    }
}

// K3: out-projection, pure streaming (identical to round-4 vq_out).
__global__ __launch_bounds__(256) void vq_out(
    const float* __restrict__ cb, const float* __restrict__ out_b,
    const float* __restrict__ ws, float* __restrict__ out)
{
    const float* w_out = ws + 4096;
    const float* idxf  = out + (size_t)NB * DIN * TT + NB;

    int blk  = blockIdx.x;
    int b    = blk >> 6;
    int rest = blk & 63;
    int o0   = (rest >> 4) * 128;
    int t0   = (rest & 15) * 256;
    int w    = threadIdx.x >> 6;
    int wu   = __builtin_amdgcn_readfirstlane(w);
    int lane = threadIdx.x & 63;
    int t    = t0 + 4 * lane;

    float4 iv = *(const float4*)(idxf + (size_t)b * TT + t);
    int k0 = (int)iv.x, k1 = (int)iv.y, k2 = (int)iv.z, k3 = (int)iv.w;

    float4 qa0 = ((const float4*)(cb))[2 * k0], qb0 = ((const float4*)(cb))[2 * k0 + 1];
    float4 qa1 = ((const float4*)(cb))[2 * k1], qb1 = ((const float4*)(cb))[2 * k1 + 1];
    float4 qa2 = ((const float4*)(cb))[2 * k2], qb2 = ((const float4*)(cb))[2 * k2 + 1];
    float4 qa3 = ((const float4*)(cb))[2 * k3], qb3 = ((const float4*)(cb))[2 * k3 + 1];

    int ob = o0 + wu * 32;
    float* outp = out + (size_t)b * DIN * TT + t;

    #pragma unroll 4
    for (int oo = 0; oo < 32; ++oo) {
        int o = ob + oo;
        const float* wo = w_out + o * DCB;   // uniform -> s_load_dwordx8
        float obias = out_b[o];
        float a0, a1, a2, a3;
        a0 = fmaf(wo[0], qa0.x, fmaf(wo[1], qa0.y, fmaf(wo[2], qa0.z, fmaf(wo[3], qa0.w,
             fmaf(wo[4], qb0.x, fmaf(wo[5], qb0.y, fmaf(wo[6], qb0.z, wo[7] * qb0.w)))))));
        a1 = fmaf(wo[0], qa1.x, fmaf(wo[1], qa1.y, fmaf(wo[2], qa1.z, fmaf(wo[3], qa1.w,
             fmaf(wo[4], qb1.x, fmaf(wo[5], qb1.y, fmaf(wo[6], qb1.z, wo[7] * qb1.w)))))));
        a2 = fmaf(wo[0], qa2.x, fmaf(wo[1], qa2.y, fmaf(wo[2], qa2.z, fmaf(wo[3], qa2.w,
             fmaf(wo[4], qb2.x, fmaf(wo[5], qb2.y, fmaf(wo[6], qb2.z, wo[7] * qb2.w)))))));
        a3 = fmaf(wo[0], qa3.x, fmaf(wo[1], qa3.y, fmaf(wo[2], qa3.z, fmaf(wo[3], qa3.w,
             fmaf(wo[4], qb3.x, fmaf(wo[5], qb3.y, fmaf(wo[6], qb3.z, wo[7] * qb3.w)))))));
        float4 r = make_float4(a0 + obias, a1 + obias, a2 + obias, a3 + obias);
        *(float4*)(outp + (size_t)o * TT) = r;
    }
}

// commit reduce, main path: 1024 partials, 64 per b
__global__ __launch_bounds__(64) void vq_commit(
    const float* __restrict__ ws_commit, float* __restrict__ out)
{
    int b    = blockIdx.x;
    int lane = threadIdx.x;
    float s = ws_commit[b * 64 + lane];
    #pragma unroll
    for (int off = 32; off > 0; off >>= 1) s += __shfl_xor(s, off, 64);
    if (lane == 0)
        out[(size_t)NB * DIN * TT + b] = s * (1.0f / (DCB * TT));
}

// ---------------- fallback path (round-4 fused, ws too small) ----------------

#define NWF 8
#define TCF 128

__global__ __launch_bounds__(512, 4) void vq_main_fb(
    const float* __restrict__ z, const float* __restrict__ in_b,
    const float* __restrict__ out_b, const float* __restrict__ cb,
    const float* __restrict__ ws, float* __restrict__ ws_commit,
    float* __restrict__ out)
{
    const float* w_inT = ws;
    const float* w_out = ws + 4096;
    const float* cb2   = ws + 8192;

    __shared__ float red[NWF][DCB][TCF];
    __shared__ float sd[NWF][TCF];
    __shared__ int   si[NWF][TCF];
    __shared__ float scl[NWF];

    int w    = threadIdx.x >> 6;
    int wu   = __builtin_amdgcn_readfirstlane(w);
    int lane = threadIdx.x & 63;
    int blk  = blockIdx.x;
    int b    = blk >> 5;
    int t0   = (blk & 31) * TCF;
    int tl   = 2 * lane;

    const float* zp = z + (size_t)b * DIN * TT + t0 + tl;

    float ze0[DCB], ze1[DCB];
    #pragma unroll
    for (int c = 0; c < DCB; ++c) { ze0[c] = 0.f; ze1[c] = 0.f; }

    int d0 = wu * 64;
    #pragma unroll 4
    for (int dd = 0; dd < 64; ++dd) {
        int d = d0 + dd;
        float2 zv = *(const float2*)(zp + (size_t)d * TT);
        const float* wi = w_inT + d * DCB;
        #pragma unroll
        for (int c = 0; c < DCB; ++c) {
            ze0[c] = fmaf(wi[c], zv.x, ze0[c]);
            ze1[c] = fmaf(wi[c], zv.y, ze1[c]);
        }
    }
    #pragma unroll
    for (int c = 0; c < DCB; ++c) {
        red[w][c][tl]     = ze0[c];
        red[w][c][tl + 1] = ze1[c];
    }
    __syncthreads();
    #pragma unroll
    for (int c = 0; c < DCB; ++c) {
        float s0 = 0.f, s1 = 0.f;
        #pragma unroll
        for (int w2 = 0; w2 < NWF; ++w2) {
            s0 += red[w2][c][tl];
            s1 += red[w2][c][tl + 1];
        }
        ze0[c] = s0 + in_b[c];
        ze1[c] = s1 + in_b[c];
    }

    float enc20 = 0.f, enc21 = 0.f;
    #pragma unroll
    for (int c = 0; c < DCB; ++c) {
        enc20 += ze0[c] * ze0[c];
        enc21 += ze1[c] * ze1[c];
    }

    float best0 = 3.4e38f, best1 = 3.4e38f;
    int   bi0   = 0,       bi1   = 0;
    int   k0    = wu * 128;
    #pragma unroll 4
    for (int kk = 0; kk < 128; ++kk) {
        int k = k0 + kk;
        const float* r = cb + k * DCB;
        float dot0 = 0.f, dot1 = 0.f;
        #pragma unroll
        for (int c = 0; c < DCB; ++c) {
            dot0 = fmaf(ze0[c], r[c], dot0);
            dot1 = fmaf(ze1[c], r[c], dot1);
        }
        float c2 = cb2[k];
        float dk0 = (enc20 - 2.0f * dot0) + c2;
        float dk1 = (enc21 - 2.0f * dot1) + c2;
        if (dk0 < best0) { best0 = dk0; bi0 = k; }
        if (dk1 < best1) { best1 = dk1; bi1 = k; }
    }
    sd[w][tl]     = best0;  si[w][tl]     = bi0;
    sd[w][tl + 1] = best1;  si[w][tl + 1] = bi1;
    __syncthreads();

    float g0 = sd[0][tl], g1 = sd[0][tl + 1];
    int  gi0 = si[0][tl], gi1 = si[0][tl + 1];
    #pragma unroll
    for (int w2 = 1; w2 < NWF; ++w2) {
        float d0_ = sd[w2][tl],     d1_ = sd[w2][tl + 1];
        int   i0_ = si[w2][tl],     i1_ = si[w2][tl + 1];
        if (d0_ < g0) { g0 = d0_; gi0 = i0_; }
        if (d1_ < g1) { g1 = d1_; gi1 = i1_; }
    }

    const float* cq0 = cb + (size_t)gi0 * DCB;
    const float* cq1 = cb + (size_t)gi1 * DCB;
    float zst0[DCB], zst1[DCB];
    float cl = 0.f;
    #pragma unroll
    for (int c = 0; c < DCB; ++c) {
        float q0 = cq0[c], q1 = cq1[c];
        float f0 = ze0[c] - q0, f1 = ze1[c] - q1;
        cl = fmaf(f0, f0, cl);
        cl = fmaf(f1, f1, cl);
        zst0[c] = ze0[c] + (q0 - ze0[c]);
        zst1[c] = ze1[c] + (q1 - ze1[c]);
    }
    #pragma unroll
    for (int off = 32; off > 0; off >>= 1) cl += __shfl_xor(cl, off, 64);
    if (lane == 0) scl[w] = cl;

    if (wu == 0) {
        float2 iv = make_float2((float)gi0, (float)gi1);
        *(float2*)(out + (size_t)NB * DIN * TT + NB + (size_t)b * TT + t0 + tl) = iv;
    }

    float* outp = out + (size_t)b * DIN * TT + t0 + tl;
    int o0 = wu * 64;
    #pragma unroll 4
    for (int oo = 0; oo < 64; ++oo) {
        int o = o0 + oo;
        const float* wo = w_out + o * DCB;
        float a0 = 0.f, a1 = 0.f;
        #pragma unroll
        for (int c = 0; c < DCB; ++c) {
            a0 = fmaf(wo[c], zst0[c], a0);
            a1 = fmaf(wo[c], zst1[c], a1);
        }
        float ob = out_b[o];
        *(float2*)(outp + (size_t)o * TT) = make_float2(a0 + ob, a1 + ob);
    }

    __syncthreads();
    if (threadIdx.x == 0) {
        float s = 0.f;
        #pragma unroll
        for (int w2 = 0; w2 < NWF; ++w2) s += scl[w2];
        ws_commit[blk] = s;
    }
}

__global__ __launch_bounds__(64) void vq_commit_fb(
    const float* __restrict__ ws_commit, float* __restrict__ out)
{
    int b    = blockIdx.x;
    int lane = threadIdx.x;
    float s = (lane < 32) ? ws_commit[b * 32 + lane] : 0.f;
    #pragma unroll
    for (int off = 32; off > 0; off >>= 1) s += __shfl_xor(s, off, 64);
    if (lane == 0)
        out[(size_t)NB * DIN * TT + b] = s * (1.0f / (DCB * TT));
}

extern "C" void kernel_launch(void* const* d_in, const int* in_sizes, int n_in,
                              void* d_out, int out_size, void* d_ws, size_t ws_size,
                              hipStream_t stream) {
    const float* z     = (const float*)d_in[0];
    const float* in_v  = (const float*)d_in[1];
    const float* in_g  = (const float*)d_in[2];
    const float* in_b  = (const float*)d_in[3];
    const float* out_v = (const float*)d_in[4];
    const float* out_g = (const float*)d_in[5];
    const float* out_b = (const float*)d_in[6];
    const float* cb    = (const float*)d_in[7];

    float* ws  = (float*)d_ws;
    float* out = (float*)d_out;

    vq_setup<<<1, 512, 0, stream>>>(in_v, in_g, out_v, out_g, cb, ws);

    if (ws_size >= WS_NEED) {
        vq_zepart<<<512, 256, 0, stream>>>(z, ws, ws + ZEP_OFF);
        vq_scan<<<1024, 256, 0, stream>>>(cb, in_b, ws, ws + 9216, out);
        vq_out<<<1024, 256, 0, stream>>>(cb, out_b, ws, out);
        vq_commit<<<NB, 64, 0, stream>>>(ws + 9216, out);
    } else {
        vq_main_fb<<<512, 512, 0, stream>>>(z, in_b, out_b, cb, ws, ws + 9216, out);
        vq_commit_fb<<<NB, 64, 0, stream>>>(ws + 9216, out);
    }
}

// Round 7
// 77.671 us; speedup vs baseline: 1.6169x; 1.6169x over previous
//
#include <hip/hip_runtime.h>
#include <math.h>

#define NB 16
#define DIN 512
#define TT 4096
#define DCB 8
#define KC 1024
#define NW 8            // waves per block
#define TC 128          // t-chunk per block (2 per lane, float2)

// ws layout (floats):
// [0,4096)      w_inT[d][c]   (transposed)
// [4096,8192)   w_out[o][c]
// [8192,9216)   cb2[k]
// [9216,9728)   per-block commit partials (512)

__global__ __launch_bounds__(512) void vq_setup(
    const float* __restrict__ in_v, const float* __restrict__ in_g,
    const float* __restrict__ out_v, const float* __restrict__ out_g,
    const float* __restrict__ cb, float* __restrict__ ws)
{
    int tid = threadIdx.x;
    float* w_inT = ws;
    float* w_out = ws + 4096;
    float* cb2   = ws + 8192;

    {   // w_in: 8 rows of 512; one wave per row
        int c    = tid >> 6;
        int lane = tid & 63;
        const float* v = in_v + c * DIN;
        float s = 0.f;
        #pragma unroll
        for (int i = 0; i < DIN; i += 64) {
            float x = v[i + lane];
            s += x * x;
        }
        #pragma unroll
        for (int off = 32; off > 0; off >>= 1) s += __shfl_xor(s, off, 64);
        float sq = sqrtf(s);
        float g  = in_g[c];
        #pragma unroll
        for (int i = 0; i < DIN; i += 64) {
            int d = i + lane;
            w_inT[d * DCB + c] = (g * v[d]) / sq;
        }
    }
    {   // w_out: 512 rows of 8
        int o = tid;
        const float* v = out_v + o * DCB;
        float s = 0.f;
        #pragma unroll
        for (int c = 0; c < DCB; ++c) s += v[c] * v[c];
        float sq = sqrtf(s);
        float g  = out_g[o];
        #pragma unroll
        for (int c = 0; c < DCB; ++c) w_out[o * DCB + c] = (g * v[c]) / sq;
    }
    for (int k = tid; k < KC; k += 512) {
        const float* r = cb + k * DCB;
        float s = 0.f;
        #pragma unroll
        for (int c = 0; c < DCB; ++c) s += r[c] * r[c];
        cb2[k] = s;
    }
}

// Fused main kernel. 512 blocks x 512 threads; block = (b, 128-t chunk).
// wave w owns d in [64w,64w+64), k in [128w,128w+128), o in [64w,64w+64).
// cb/cb2 and (later) w_out/out_b are LDS-staged; all scan/out-proj table
// reads are wave-uniform LDS broadcasts.
__global__ __launch_bounds__(512, 4) void vq_main(
    const float* __restrict__ z, const float* __restrict__ in_b,
    const float* __restrict__ out_b, const float* __restrict__ cb,
    const float* __restrict__ ws, float* __restrict__ ws_commit,
    float* __restrict__ out)
{
    __shared__ float s_cb[KC * DCB];        // 32 KB  [k][c]
    __shared__ float s_cb2[KC];             // 4 KB
    __shared__ float s_red[NW * DCB * TC];  // 32 KB, reused for w_out/out_b
    __shared__ float s_sd[NW][TC];          // 4 KB
    __shared__ int   s_si[NW][TC];          // 4 KB

    const float* w_inT = ws;

    int tid  = threadIdx.x;
    int w    = tid >> 6;
    int wu   = __builtin_amdgcn_readfirstlane(w);
    int lane = tid & 63;
    int blk  = blockIdx.x;               // 0..511
    int b    = blk >> 5;
    int t0   = (blk & 31) * TC;
    int tl   = 2 * lane;

    // prefetch block-shared tables into VGPRs (hidden under in-projection)
    float4 cbs0 = ((const float4*)cb)[tid];
    float4 cbs1 = ((const float4*)cb)[512 + tid];
    float4 cbs2 = ((const float4*)cb)[1024 + tid];
    float4 cbs3 = ((const float4*)cb)[1536 + tid];
    float4 cb2s = make_float4(0.f, 0.f, 0.f, 0.f);
    if (tid < 256) cb2s = ((const float4*)(ws + 8192))[tid];
    float4 wos0 = ((const float4*)(ws + 4096))[tid];
    float4 wos1 = ((const float4*)(ws + 4096))[512 + tid];
    float4 obs  = make_float4(0.f, 0.f, 0.f, 0.f);
    if (tid < 128) obs = ((const float4*)out_b)[tid];

    const float* zp = z + (size_t)b * DIN * TT + t0 + tl;

    // ---- partial in-projection over d in [wu*64, wu*64+64), float2 over t ----
    float ze0[DCB], ze1[DCB];
    #pragma unroll
    for (int c = 0; c < DCB; ++c) { ze0[c] = 0.f; ze1[c] = 0.f; }

    int d0 = wu * 64;
    #pragma unroll 4
    for (int dd = 0; dd < 64; ++dd) {
        int d = d0 + dd;
        float2 zv = *(const float2*)(zp + (size_t)d * TT);  // 512 B/wave
        const float* wi = w_inT + d * DCB;                  // uniform -> s_load
        #pragma unroll
        for (int c = 0; c < DCB; ++c) {
            ze0[c] = fmaf(wi[c], zv.x, ze0[c]);
            ze1[c] = fmaf(wi[c], zv.y, ze1[c]);
        }
    }

    // ---- stage cb tables + write red partials ----
    ((float4*)s_cb)[tid]        = cbs0;
    ((float4*)s_cb)[512 + tid]  = cbs1;
    ((float4*)s_cb)[1024 + tid] = cbs2;
    ((float4*)s_cb)[1536 + tid] = cbs3;
    if (tid < 256) ((float4*)s_cb2)[tid] = cb2s;

    float* redw = s_red + w * DCB * TC;
    #pragma unroll
    for (int c = 0; c < DCB; ++c) {
        redw[c * TC + tl]     = ze0[c];
        redw[c * TC + tl + 1] = ze1[c];
    }
    __syncthreads();   // (1) red + staged cb visible

    // ---- cross-wave reduce of ze ----
    #pragma unroll
    for (int c = 0; c < DCB; ++c) {
        float s0 = 0.f, s1 = 0.f;
        #pragma unroll
        for (int w2 = 0; w2 < NW; ++w2) {
            s0 += s_red[(w2 * DCB + c) * TC + tl];
            s1 += s_red[(w2 * DCB + c) * TC + tl + 1];
        }
        ze0[c] = s0 + in_b[c];
        ze1[c] = s1 + in_b[c];
    }
    __syncthreads();   // (2) all red reads done -> red space reusable

    // ---- overwrite red space with w_out / out_b ----
    float* s_wout = s_red;              // 4096 floats [o][c]
    float* s_outb = s_red + DIN * DCB;  // 512 floats
    ((float4*)s_wout)[tid]       = wos0;
    ((float4*)s_wout)[512 + tid] = wos1;
    if (tid < 128) ((float4*)s_outb)[tid] = obs;
    // ordered vs readers by barrier (3)

    float enc20 = 0.f, enc21 = 0.f;
    #pragma unroll
    for (int c = 0; c < DCB; ++c) {
        enc20 += ze0[c] * ze0[c];
        enc21 += ze1[c] * ze1[c];
    }

    // ---- codebook partial argmin over k in [wu*128, wu*128+128), LDS reads ----
    float best0 = 3.4e38f, best1 = 3.4e38f;
    int   bi0   = 0,       bi1   = 0;
    int   k0    = wu * 128;
    #pragma unroll 4
    for (int kk = 0; kk < 128; ++kk) {
        int k = k0 + kk;
        float4 r0 = ((const float4*)s_cb)[2 * k];       // uniform -> broadcast
        float4 r1 = ((const float4*)s_cb)[2 * k + 1];
        float dot0 = fmaf(ze0[0], r0.x, fmaf(ze0[1], r0.y, fmaf(ze0[2], r0.z, fmaf(ze0[3], r0.w,
                     fmaf(ze0[4], r1.x, fmaf(ze0[5], r1.y, fmaf(ze0[6], r1.z, ze0[7] * r1.w)))))));
        float dot1 = fmaf(ze1[0], r0.x, fmaf(ze1[1], r0.y, fmaf(ze1[2], r0.z, fmaf(ze1[3], r0.w,
                     fmaf(ze1[4], r1.x, fmaf(ze1[5], r1.y, fmaf(ze1[6], r1.z, ze1[7] * r1.w)))))));
        float c2  = s_cb2[k];
        float dk0 = (enc20 - 2.0f * dot0) + c2;
        float dk1 = (enc21 - 2.0f * dot1) + c2;
        if (dk0 < best0) { best0 = dk0; bi0 = k; }
        if (dk1 < best1) { best1 = dk1; bi1 = k; }
    }
    s_sd[w][tl]     = best0;  s_si[w][tl]     = bi0;
    s_sd[w][tl + 1] = best1;  s_si[w][tl + 1] = bi1;
    __syncthreads();   // (3) sd/si + staged w_out visible

    // ---- ordered combine (w'=0..7, strict < keeps first min over k) ----
    float g0 = s_sd[0][tl], g1 = s_sd[0][tl + 1];
    int  gi0 = s_si[0][tl], gi1 = s_si[0][tl + 1];
    #pragma unroll
    for (int w2 = 1; w2 < NW; ++w2) {
        float d0_ = s_sd[w2][tl],     d1_ = s_sd[w2][tl + 1];
        int   i0_ = s_si[w2][tl],     i1_ = s_si[w2][tl + 1];
        if (d0_ < g0) { g0 = d0_; gi0 = i0_; }
        if (d1_ < g1) { g1 = d1_; gi1 = i1_; }
    }

    // ---- z_q rows from LDS ----
    float4 q0a = ((const float4*)s_cb)[2 * gi0], q0b = ((const float4*)s_cb)[2 * gi0 + 1];
    float4 q1a = ((const float4*)s_cb)[2 * gi1], q1b = ((const float4*)s_cb)[2 * gi1 + 1];

    // ---- commit loss + indices: wave 0 ONLY (fixes 8x overcount) ----
    if (wu == 0) {
        float cl = 0.f;
        float f;
        f = ze0[0]-q0a.x; cl = fmaf(f,f,cl);  f = ze1[0]-q1a.x; cl = fmaf(f,f,cl);
        f = ze0[1]-q0a.y; cl = fmaf(f,f,cl);  f = ze1[1]-q1a.y; cl = fmaf(f,f,cl);
        f = ze0[2]-q0a.z; cl = fmaf(f,f,cl);  f = ze1[2]-q1a.z; cl = fmaf(f,f,cl);
        f = ze0[3]-q0a.w; cl = fmaf(f,f,cl);  f = ze1[3]-q1a.w; cl = fmaf(f,f,cl);
        f = ze0[4]-q0b.x; cl = fmaf(f,f,cl);  f = ze1[4]-q1b.x; cl = fmaf(f,f,cl);
        f = ze0[5]-q0b.y; cl = fmaf(f,f,cl);  f = ze1[5]-q1b.y; cl = fmaf(f,f,cl);
        f = ze0[6]-q0b.z; cl = fmaf(f,f,cl);  f = ze1[6]-q1b.z; cl = fmaf(f,f,cl);
        f = ze0[7]-q0b.w; cl = fmaf(f,f,cl);  f = ze1[7]-q1b.w; cl = fmaf(f,f,cl);
        #pragma unroll
        for (int off = 32; off > 0; off >>= 1) cl += __shfl_xor(cl, off, 64);
        if (lane == 0) ws_commit[blk] = cl;
        // indices (as float; whole out buffer is read as fp32)
        float2 iv = make_float2((float)gi0, (float)gi1);
        *(float2*)(out + (size_t)NB * DIN * TT + NB + (size_t)b * TT + t0 + tl) = iv;
    }

    // ---- out-projection over o in [wu*64, wu*64+64), LDS broadcast reads ----
    float* outp = out + (size_t)b * DIN * TT + t0 + tl;
    int o0 = wu * 64;
    #pragma unroll 4
    for (int oo = 0; oo < 64; ++oo) {
        int o = o0 + oo;
        float4 wa = ((const float4*)s_wout)[2 * o];     // uniform -> broadcast
        float4 wb = ((const float4*)s_wout)[2 * o + 1];
        float obias = s_outb[o];
        float a0 = fmaf(wa.x, q0a.x, fmaf(wa.y, q0a.y, fmaf(wa.z, q0a.z, fmaf(wa.w, q0a.w,
                   fmaf(wb.x, q0b.x, fmaf(wb.y, q0b.y, fmaf(wb.z, q0b.z, wb.w * q0b.w)))))));
        float a1 = fmaf(wa.x, q1a.x, fmaf(wa.y, q1a.y, fmaf(wa.z, q1a.z, fmaf(wa.w, q1a.w,
                   fmaf(wb.x, q1b.x, fmaf(wb.y, q1b.y, fmaf(wb.z, q1b.z, wb.w * q1b.w)))))));
        *(float2*)(outp + (size_t)o * TT) = make_float2(a0 + obias, a1 + obias);
    }
}

__global__ __launch_bounds__(64) void vq_commit(
    const float* __restrict__ ws_commit, float* __restrict__ out)
{
    int b    = blockIdx.x;
    int lane = threadIdx.x;
    float s = (lane < 32) ? ws_commit[b * 32 + lane] : 0.f;
    #pragma unroll
    for (int off = 32; off > 0; off >>= 1) s += __shfl_xor(s, off, 64);
    if (lane == 0)
        out[(size_t)NB * DIN * TT + b] = s * (1.0f / (DCB * TT));
}

extern "C" void kernel_launch(void* const* d_in, const int* in_sizes, int n_in,
                              void* d_out, int out_size, void* d_ws, size_t ws_size,
                              hipStream_t stream) {
    const float* z     = (const float*)d_in[0];
    const float* in_v  = (const float*)d_in[1];
    const float* in_g  = (const float*)d_in[2];
    const float* in_b  = (const float*)d_in[3];
    const float* out_v = (const float*)d_in[4];
    const float* out_g = (const float*)d_in[5];
    const float* out_b = (const float*)d_in[6];
    const float* cb    = (const float*)d_in[7];

    float* ws  = (float*)d_ws;
    float* out = (float*)d_out;

    vq_setup<<<1, 512, 0, stream>>>(in_v, in_g, out_v, out_g, cb, ws);
    vq_main<<<512, 512, 0, stream>>>(z, in_b, out_b, cb, ws, ws + 9216, out);
    vq_commit<<<NB, 64, 0, stream>>>(ws + 9216, out);
}

// Round 8
// 70.864 us; speedup vs baseline: 1.7722x; 1.0961x over previous
//
#include <hip/hip_runtime.h>
#include <math.h>

#define NB 16
#define DIN 512
#define TT 4096
#define DCB 8
#define KC 1024
#define NW 8            // waves per block
#define TC 128          // t-chunk per block (2 per lane, float2)

// ws layout (floats):
// [0,4096)      w_inT[d][c]   (transposed)
// [4096,8192)   w_out[o][c]
// [8192,9216)   cb2[k]
// [9216,9728)   per-block commit partials (512)

__global__ __launch_bounds__(512) void vq_setup(
    const float* __restrict__ in_v, const float* __restrict__ in_g,
    const float* __restrict__ out_v, const float* __restrict__ out_g,
    const float* __restrict__ cb, float* __restrict__ ws)
{
    int tid = threadIdx.x;
    float* w_inT = ws;
    float* w_out = ws + 4096;
    float* cb2   = ws + 8192;

    {   // w_in: 8 rows of 512; one wave per row
        int c    = tid >> 6;
        int lane = tid & 63;
        const float* v = in_v + c * DIN;
        float s = 0.f;
        #pragma unroll
        for (int i = 0; i < DIN; i += 64) {
            float x = v[i + lane];
            s += x * x;
        }
        #pragma unroll
        for (int off = 32; off > 0; off >>= 1) s += __shfl_xor(s, off, 64);
        float sq = sqrtf(s);
        float g  = in_g[c];
        #pragma unroll
        for (int i = 0; i < DIN; i += 64) {
            int d = i + lane;
            w_inT[d * DCB + c] = (g * v[d]) / sq;
        }
    }
    {   // w_out: 512 rows of 8
        int o = tid;
        const float* v = out_v + o * DCB;
        float s = 0.f;
        #pragma unroll
        for (int c = 0; c < DCB; ++c) s += v[c] * v[c];
        float sq = sqrtf(s);
        float g  = out_g[o];
        #pragma unroll
        for (int c = 0; c < DCB; ++c) w_out[o * DCB + c] = (g * v[c]) / sq;
    }
    for (int k = tid; k < KC; k += 512) {
        const float* r = cb + k * DCB;
        float s = 0.f;
        #pragma unroll
        for (int c = 0; c < DCB; ++c) s += r[c] * r[c];
        cb2[k] = s;
    }
}

// Fused main kernel. 512 blocks x 512 threads; block = (b, 128-t chunk).
// wave w owns d in [64w,64w+64), k in [128w,128w+128), o in [64w,64w+64).
// cb/cb2 staged to LDS at kernel TOP (short register live range — r7's
// spills came from holding the prefetch across the in-proj loop).
// w_out/out_b read via wave-uniform s_load in the epilogue (r4-proven).
__global__ __launch_bounds__(512, 4) void vq_main(
    const float* __restrict__ z, const float* __restrict__ in_b,
    const float* __restrict__ out_b, const float* __restrict__ cb,
    const float* __restrict__ ws, float* __restrict__ ws_commit,
    float* __restrict__ out)
{
    __shared__ float s_cb[KC * DCB];        // 32 KB  [k][c]
    __shared__ float s_cb2[KC];             // 4 KB
    __shared__ float s_red[NW * DCB * TC];  // 32 KB
    __shared__ float s_sd[NW][TC];          // 4 KB
    __shared__ int   s_si[NW][TC];          // 4 KB

    const float* w_inT = ws;
    const float* w_out = ws + 4096;

    int tid  = threadIdx.x;
    int w    = tid >> 6;
    int wu   = __builtin_amdgcn_readfirstlane(w);
    int lane = tid & 63;
    int blk  = blockIdx.x;               // 0..511
    int b    = blk >> 5;
    int t0   = (blk & 31) * TC;
    int tl   = 2 * lane;

    // ---- stage cb + cb2 into LDS immediately (short live range) ----
    {
        float4 c0 = ((const float4*)cb)[tid];
        float4 c1 = ((const float4*)cb)[512 + tid];
        float4 c2 = ((const float4*)cb)[1024 + tid];
        float4 c3 = ((const float4*)cb)[1536 + tid];
        ((float4*)s_cb)[tid]        = c0;
        ((float4*)s_cb)[512 + tid]  = c1;
        ((float4*)s_cb)[1024 + tid] = c2;
        ((float4*)s_cb)[1536 + tid] = c3;
        if (tid < 256) {
            float4 q = ((const float4*)(ws + 8192))[tid];
            ((float4*)s_cb2)[tid] = q;
        }
    }

    const float* zp = z + (size_t)b * DIN * TT + t0 + tl;

    // ---- partial in-projection over d in [wu*64, wu*64+64), float2 over t ----
    float ze0[DCB], ze1[DCB];
    #pragma unroll
    for (int c = 0; c < DCB; ++c) { ze0[c] = 0.f; ze1[c] = 0.f; }

    int d0 = wu * 64;
    #pragma unroll 4
    for (int dd = 0; dd < 64; ++dd) {
        int d = d0 + dd;
        float2 zv = *(const float2*)(zp + (size_t)d * TT);  // 512 B/wave
        const float* wi = w_inT + d * DCB;                  // uniform -> s_load
        #pragma unroll
        for (int c = 0; c < DCB; ++c) {
            ze0[c] = fmaf(wi[c], zv.x, ze0[c]);
            ze1[c] = fmaf(wi[c], zv.y, ze1[c]);
        }
    }

    // ---- write red partials ----
    float* redw = s_red + w * DCB * TC;
    #pragma unroll
    for (int c = 0; c < DCB; ++c) {
        redw[c * TC + tl]     = ze0[c];
        redw[c * TC + tl + 1] = ze1[c];
    }
    __syncthreads();   // (1) red + staged cb/cb2 visible

    // ---- cross-wave reduce of ze ----
    #pragma unroll
    for (int c = 0; c < DCB; ++c) {
        float s0 = 0.f, s1 = 0.f;
        #pragma unroll
        for (int w2 = 0; w2 < NW; ++w2) {
            s0 += s_red[(w2 * DCB + c) * TC + tl];
            s1 += s_red[(w2 * DCB + c) * TC + tl + 1];
        }
        ze0[c] = s0 + in_b[c];
        ze1[c] = s1 + in_b[c];
    }

    float enc20 = 0.f, enc21 = 0.f;
    #pragma unroll
    for (int c = 0; c < DCB; ++c) {
        enc20 += ze0[c] * ze0[c];
        enc21 += ze1[c] * ze1[c];
    }

    // ---- codebook partial argmin over k in [wu*128, wu*128+128), LDS reads ----
    float best0 = 3.4e38f, best1 = 3.4e38f;
    int   bi0   = 0,       bi1   = 0;
    int   k0    = wu * 128;
    #pragma unroll 4
    for (int kk = 0; kk < 128; ++kk) {
        int k = k0 + kk;
        float4 r0 = ((const float4*)s_cb)[2 * k];       // uniform -> broadcast
        float4 r1 = ((const float4*)s_cb)[2 * k + 1];
        float dot0 = fmaf(ze0[0], r0.x, fmaf(ze0[1], r0.y, fmaf(ze0[2], r0.z, fmaf(ze0[3], r0.w,
                     fmaf(ze0[4], r1.x, fmaf(ze0[5], r1.y, fmaf(ze0[6], r1.z, ze0[7] * r1.w)))))));
        float dot1 = fmaf(ze1[0], r0.x, fmaf(ze1[1], r0.y, fmaf(ze1[2], r0.z, fmaf(ze1[3], r0.w,
                     fmaf(ze1[4], r1.x, fmaf(ze1[5], r1.y, fmaf(ze1[6], r1.z, ze1[7] * r1.w)))))));
        float c2  = s_cb2[k];
        float dk0 = (enc20 - 2.0f * dot0) + c2;
        float dk1 = (enc21 - 2.0f * dot1) + c2;
        if (dk0 < best0) { best0 = dk0; bi0 = k; }
        if (dk1 < best1) { best1 = dk1; bi1 = k; }
    }
    s_sd[w][tl]     = best0;  s_si[w][tl]     = bi0;
    s_sd[w][tl + 1] = best1;  s_si[w][tl + 1] = bi1;
    __syncthreads();   // (2) sd/si visible

    // ---- ordered combine (w'=0..7, strict < keeps first min over k) ----
    float g0 = s_sd[0][tl], g1 = s_sd[0][tl + 1];
    int  gi0 = s_si[0][tl], gi1 = s_si[0][tl + 1];
    #pragma unroll
    for (int w2 = 1; w2 < NW; ++w2) {
        float d0_ = s_sd[w2][tl],     d1_ = s_sd[w2][tl + 1];
        int   i0_ = s_si[w2][tl],     i1_ = s_si[w2][tl + 1];
        if (d0_ < g0) { g0 = d0_; gi0 = i0_; }
        if (d1_ < g1) { g1 = d1_; gi1 = i1_; }
    }

    // ---- z_q rows from LDS ----
    float4 q0a = ((const float4*)s_cb)[2 * gi0], q0b = ((const float4*)s_cb)[2 * gi0 + 1];
    float4 q1a = ((const float4*)s_cb)[2 * gi1], q1b = ((const float4*)s_cb)[2 * gi1 + 1];

    // ---- commit loss + indices: wave 0 ONLY ----
    if (wu == 0) {
        float cl = 0.f;
        float f;
        f = ze0[0]-q0a.x; cl = fmaf(f,f,cl);  f = ze1[0]-q1a.x; cl = fmaf(f,f,cl);
        f = ze0[1]-q0a.y; cl = fmaf(f,f,cl);  f = ze1[1]-q1a.y; cl = fmaf(f,f,cl);
        f = ze0[2]-q0a.z; cl = fmaf(f,f,cl);  f = ze1[2]-q1a.z; cl = fmaf(f,f,cl);
        f = ze0[3]-q0a.w; cl = fmaf(f,f,cl);  f = ze1[3]-q1a.w; cl = fmaf(f,f,cl);
        f = ze0[4]-q0b.x; cl = fmaf(f,f,cl);  f = ze1[4]-q1b.x; cl = fmaf(f,f,cl);
        f = ze0[5]-q0b.y; cl = fmaf(f,f,cl);  f = ze1[5]-q1b.y; cl = fmaf(f,f,cl);
        f = ze0[6]-q0b.z; cl = fmaf(f,f,cl);  f = ze1[6]-q1b.z; cl = fmaf(f,f,cl);
        f = ze0[7]-q0b.w; cl = fmaf(f,f,cl);  f = ze1[7]-q1b.w; cl = fmaf(f,f,cl);
        #pragma unroll
        for (int off = 32; off > 0; off >>= 1) cl += __shfl_xor(cl, off, 64);
        if (lane == 0) ws_commit[blk] = cl;
        // indices (as float; whole out buffer is read as fp32)
        float2 iv = make_float2((float)gi0, (float)gi1);
        *(float2*)(out + (size_t)NB * DIN * TT + NB + (size_t)b * TT + t0 + tl) = iv;
    }

    // ---- out-projection over o in [wu*64, wu*64+64), s_load weights ----
    float* outp = out + (size_t)b * DIN * TT + t0 + tl;
    int o0 = wu * 64;
    #pragma unroll 4
    for (int oo = 0; oo < 64; ++oo) {
        int o = o0 + oo;
        const float* wo = w_out + o * DCB;   // uniform -> s_load_dwordx8
        float obias = out_b[o];              // uniform -> s_load
        float a0 = fmaf(wo[0], q0a.x, fmaf(wo[1], q0a.y, fmaf(wo[2], q0a.z, fmaf(wo[3], q0a.w,
                   fmaf(wo[4], q0b.x, fmaf(wo[5], q0b.y, fmaf(wo[6], q0b.z, wo[7] * q0b.w)))))));
        float a1 = fmaf(wo[0], q1a.x, fmaf(wo[1], q1a.y, fmaf(wo[2], q1a.z, fmaf(wo[3], q1a.w,
                   fmaf(wo[4], q1b.x, fmaf(wo[5], q1b.y, fmaf(wo[6], q1b.z, wo[7] * q1b.w)))))));
        *(float2*)(outp + (size_t)o * TT) = make_float2(a0 + obias, a1 + obias);
    }
}

__global__ __launch_bounds__(64) void vq_commit(
    const float* __restrict__ ws_commit, float* __restrict__ out)
{
    int b    = blockIdx.x;
    int lane = threadIdx.x;
    float s = (lane < 32) ? ws_commit[b * 32 + lane] : 0.f;
    #pragma unroll
    for (int off = 32; off > 0; off >>= 1) s += __shfl_xor(s, off, 64);
    if (lane == 0)
        out[(size_t)NB * DIN * TT + b] = s * (1.0f / (DCB * TT));
}

extern "C" void kernel_launch(void* const* d_in, const int* in_sizes, int n_in,
                              void* d_out, int out_size, void* d_ws, size_t ws_size,
                              hipStream_t stream) {
    const float* z     = (const float*)d_in[0];
    const float* in_v  = (const float*)d_in[1];
    const float* in_g  = (const float*)d_in[2];
    const float* in_b  = (const float*)d_in[3];
    const float* out_v = (const float*)d_in[4];
    const float* out_g = (const float*)d_in[5];
    const float* out_b = (const float*)d_in[6];
    const float* cb    = (const float*)d_in[7];

    float* ws  = (float*)d_ws;
    float* out = (float*)d_out;

    vq_setup<<<1, 512, 0, stream>>>(in_v, in_g, out_v, out_g, cb, ws);
    vq_main<<<512, 512, 0, stream>>>(z, in_b, out_b, cb, ws, ws + 9216, out);
    vq_commit<<<NB, 64, 0, stream>>>(ws + 9216, out);
}